// Round 11
// baseline (119.191 us; speedup 1.0000x reference)
//
#include <hip/hip_runtime.h>
#include <hip/hip_bf16.h>
#include <cstdint>
#include <cstddef>

#define NN 10000
#define NE 160000
#define DD 300
#define KP 320      // K padded to 10 MFMA steps of 32
#define NPAD 320    // W rows padded to 20 tiles of 16
#define MTILES 625  // NN/16
#define CAP 64      // bucket capacity per node (max degree ~35 for this graph)

using bf16x8 = __attribute__((ext_vector_type(8))) __bf16;
using f32x4  = __attribute__((ext_vector_type(4))) float;

// ---------------- K1: zero cnt + convert W1,W2 -> bf16 [NPAD][KP] ----------------

__global__ __launch_bounds__(256) void zero_convw_kernel(const float* __restrict__ W1,
                                                         const float* __restrict__ W2,
                                                         __bf16* __restrict__ W1b,
                                                         __bf16* __restrict__ W2b,
                                                         int* __restrict__ cnt) {
    const int t = blockIdx.x * 256 + threadIdx.x;   // 0..12799
    if (t < NN) cnt[t] = 0;
    const int n = t / (KP / 8);          // 0..319
    const int k0 = (t % (KP / 8)) * 8;   // 0..312
    bf16x8 v1, v2;
#pragma unroll
    for (int i = 0; i < 8; ++i) {
        const int k = k0 + i;
        const bool in = (n < DD) && (k < DD);
        v1[i] = (__bf16)(in ? W1[n * DD + k] : 0.f);
        v2[i] = (__bf16)(in ? W2[n * DD + k] : 0.f);
    }
    *(bf16x8*)(W1b + (size_t)n * KP + k0) = v1;
    *(bf16x8*)(W2b + (size_t)n * KP + k0) = v2;
}

// ---------------- K2: bucket fill ----------------

__global__ void bucket_kernel(const int* __restrict__ src, const int* __restrict__ dst,
                              int* __restrict__ cnt, int* __restrict__ bucket) {
    int e = blockIdx.x * 256 + threadIdx.x;
    if (e < NE) {
        int d = dst[e];
        int pos = atomicAdd(&cnt[d], 1);
        if (pos < CAP) bucket[d * CAP + pos] = src[e];
    }
}

// ---------------- GEMM: G[m][n] = sum_k A[m][k]*W[n][k]  (bf16 out, no bias) ----------------
// REPS>1: repeat the whole M-sweep with idempotent stores (diagnostic timing only).

template <bool F32IN, int REPS>
__global__ __launch_bounds__(256, 1) void gemm_kernel(const void* __restrict__ Ap,
                                                      const __bf16* __restrict__ Wb,
                                                      __bf16* __restrict__ G) {
    const int w = threadIdx.x >> 6;
    const int lane = threadIdx.x & 63;
    const int r = lane & 15;    // A row-in-tile / B col / D col
    const int q = lane >> 4;    // k-block select / D row-block

    bf16x8 b[5][10];
    const __bf16* Bb = Wb + (size_t)r * KP + q * 8;
#pragma unroll
    for (int t = 0; t < 5; ++t) {
        const __bf16* Bt = Bb + (size_t)(w * 5 + t) * 16 * KP;
#pragma unroll
        for (int ks = 0; ks < 10; ++ks)
            b[t][ks] = *(const bf16x8*)(Bt + ks * 32);
    }

    for (int rep = 0; rep < REPS; ++rep) {
        for (int mt = blockIdx.x; mt < MTILES; mt += gridDim.x) {
            f32x4 acc[5] = {};
            if constexpr (F32IN) {
                const float* Ab = (const float*)Ap + (size_t)(mt * 16 + r) * DD + q * 8;
#pragma unroll
                for (int ks = 0; ks < 9; ++ks) {
                    f32x4 lo = *(const f32x4*)(Ab + ks * 32);
                    f32x4 hi = *(const f32x4*)(Ab + ks * 32 + 4);
                    bf16x8 af;
#pragma unroll
                    for (int j = 0; j < 4; ++j) { af[j] = (__bf16)lo[j]; af[4 + j] = (__bf16)hi[j]; }
#pragma unroll
                    for (int t = 0; t < 5; ++t)
                        acc[t] = __builtin_amdgcn_mfma_f32_16x16x32_bf16(af, b[t][ks], acc[t], 0, 0, 0);
                }
                {   // ks = 9: k = 288 + q*8 + j, guard k < 300
                    bf16x8 af;
#pragma unroll
                    for (int j = 0; j < 8; ++j) {
                        int k = 288 + q * 8 + j;
                        af[j] = (__bf16)((k < DD) ? Ab[288 + j] : 0.f);
                    }
#pragma unroll
                    for (int t = 0; t < 5; ++t)
                        acc[t] = __builtin_amdgcn_mfma_f32_16x16x32_bf16(af, b[t][9], acc[t], 0, 0, 0);
                }
            } else {
                const __bf16* Ab = (const __bf16*)Ap + (size_t)(mt * 16 + r) * KP + q * 8;
#pragma unroll
                for (int ks = 0; ks < 10; ++ks) {
                    bf16x8 af = *(const bf16x8*)(Ab + ks * 32);
#pragma unroll
                    for (int t = 0; t < 5; ++t)
                        acc[t] = __builtin_amdgcn_mfma_f32_16x16x32_bf16(af, b[t][ks], acc[t], 0, 0, 0);
                }
            }
#pragma unroll
            for (int t = 0; t < 5; ++t) {
                const int n = (w * 5 + t) * 16 + r;
#pragma unroll
                for (int j = 0; j < 4; ++j) {
                    const int m = mt * 16 + q * 4 + j;
                    G[(size_t)m * KP + n] = (__bf16)acc[t][j];
                }
            }
        }
    }
}

// ---------------- aggregation over G + bias + relu; 2 waves per node (R7 structure) ----------------
// REPS>1: full recompute + idempotent store per rep (diagnostic). Rep 2 runs L2-warm:
// if duration ~2x single, gather is latency/MSHR-bound; if <<2x, L2 residency is the lever.

template <bool LAST, int REPS>
__global__ __launch_bounds__(256) void agg_kernel(const __bf16* __restrict__ G,
                                                  const float* __restrict__ bias,
                                                  void* __restrict__ outp,
                                                  const int* __restrict__ cnt,
                                                  const int* __restrict__ bucket) {
    __shared__ float part[2][KP];
    const int w = threadIdx.x >> 6;        // 0..3
    const int lane = threadIdx.x & 63;
    const int nsub = w >> 1;               // node slot in block
    const int half = w & 1;                // 0: self + first half; 1: second half
    const int node = blockIdx.x * 2 + nsub;   // grid 5000 x 2 = 10000 exactly
    const bool act = lane < (KP / 8);      // 40 lanes x 8 bf16 = 320 cols
    const uint4* hv = (const uint4*)G;     // row stride KP/8 = 40

    const int c = min(cnt[node], CAP);
    const int h0 = c >> 1;
    const int myBase = node * CAP + (half ? h0 : 0);
    const int myCnt = half ? (c - h0) : h0;

    for (int rep = 0; rep < REPS; ++rep) {
        float acc[8] = {};
        auto addv = [&](uint4 v) {
            uint32_t u[4] = {v.x, v.y, v.z, v.w};
#pragma unroll
            for (int i = 0; i < 4; ++i) {
                acc[2 * i]     += __uint_as_float(u[i] << 16);
                acc[2 * i + 1] += __uint_as_float(u[i] & 0xffff0000u);
            }
        };

        if (!half && act) addv(hv[(size_t)node * (KP / 8) + lane]);   // self-loop

        int idx = 0;
        if (lane < myCnt) idx = bucket[myBase + lane];
        int j = 0;
        for (; j + 4 <= myCnt; j += 4) {
            int n0 = __shfl(idx, j),     n1 = __shfl(idx, j + 1);
            int n2 = __shfl(idx, j + 2), n3 = __shfl(idx, j + 3);
            if (act) {
                uint4 v0 = hv[(size_t)n0 * (KP / 8) + lane];
                uint4 v1 = hv[(size_t)n1 * (KP / 8) + lane];
                uint4 v2 = hv[(size_t)n2 * (KP / 8) + lane];
                uint4 v3 = hv[(size_t)n3 * (KP / 8) + lane];
                addv(v0); addv(v1); addv(v2); addv(v3);
            }
        }
        for (; j < myCnt; ++j) {
            int nb = __shfl(idx, j);
            if (act) addv(hv[(size_t)nb * (KP / 8) + lane]);
        }

        // combine wave pair through LDS (no early returns: all threads stay for all reps)
        if (half && act) {
            *(f32x4*)&part[nsub][lane * 8]     = (f32x4){acc[0], acc[1], acc[2], acc[3]};
            *(f32x4*)&part[nsub][lane * 8 + 4] = (f32x4){acc[4], acc[5], acc[6], acc[7]};
        }
        __syncthreads();
        if (!half && act) {
            f32x4 p0 = *(const f32x4*)&part[nsub][lane * 8];
            f32x4 p1 = *(const f32x4*)&part[nsub][lane * 8 + 4];
#pragma unroll
            for (int i = 0; i < 4; ++i) { acc[i] += p0[i]; acc[4 + i] += p1[i]; }

            const int c0 = lane * 8;
            if (LAST) {
                float* out = (float*)outp + (size_t)node * DD + c0;
#pragma unroll
                for (int i = 0; i < 8; ++i) {
                    int n = c0 + i;
                    if (n < DD) {
                        float v = acc[i] + bias[n];
                        out[i] = v > 0.f ? v : 0.f;
                    }
                }
            } else {
                bf16x8 o;
#pragma unroll
                for (int i = 0; i < 8; ++i) {
                    int n = c0 + i;
                    float v = (n < DD) ? acc[i] + bias[n] : 0.f;
                    v = v > 0.f ? v : 0.f;
                    o[i] = (__bf16)v;
                }
                *(bf16x8*)((__bf16*)outp + (size_t)node * KP + c0) = o;
            }
        }
        __syncthreads();   // protect part[] before next rep overwrites
    }
}

// ---------------- launch ----------------

extern "C" void kernel_launch(void* const* d_in, const int* in_sizes, int n_in,
                              void* d_out, int out_size, void* d_ws, size_t ws_size,
                              hipStream_t stream) {
    const float* features = (const float*)d_in[0];
    const int*   src      = (const int*)d_in[1];
    const int*   dst      = (const int*)d_in[2];
    const float* W1       = (const float*)d_in[3];
    const float* b1       = (const float*)d_in[4];
    const float* W2       = (const float*)d_in[5];
    const float* b2       = (const float*)d_in[6];
    float* out = (float*)d_out;

    char* ws = (char*)d_ws;
    size_t off = 0;
    auto alloc = [&](size_t bytes) -> void* {
        void* p = ws + off;
        off += (bytes + 255) & ~(size_t)255;
        return p;
    };
    int*    cnt    = (int*)alloc(NN * sizeof(int));
    int*    bucket = (int*)alloc((size_t)NN * CAP * sizeof(int));
    __bf16* W1b    = (__bf16*)alloc((size_t)NPAD * KP * sizeof(__bf16));
    __bf16* W2b    = (__bf16*)alloc((size_t)NPAD * KP * sizeof(__bf16));
    __bf16* Gbuf   = (__bf16*)alloc((size_t)NN * KP * sizeof(__bf16));
    __bf16* h1b    = (__bf16*)alloc((size_t)NN * KP * sizeof(__bf16));
    (void)ws_size; (void)in_sizes; (void)n_in; (void)out_size;

    // K1: zero cnt + convert W
    hipLaunchKernelGGL(zero_convw_kernel, dim3(50), dim3(256), 0, stream, W1, W2, W1b, W2b, cnt);
    // K2: bucket fill
    hipLaunchKernelGGL(bucket_kernel, dim3((NE + 255) / 256), dim3(256), 0, stream, src, dst, cnt, bucket);

    // layer 1 (DIAGNOSTIC REPS=2 on both heavy kernels; layer 2 stays single as control)
    hipLaunchKernelGGL((gemm_kernel<true, 2>), dim3(256), dim3(256), 0, stream,
                       (const void*)features, W1b, Gbuf);
    hipLaunchKernelGGL((agg_kernel<false, 2>), dim3(NN / 2), dim3(256), 0, stream,
                       Gbuf, b1, (void*)h1b, cnt, bucket);
    // layer 2: G2 = h1 . W2^T ; out = relu(agg(G2) + b2)
    hipLaunchKernelGGL((gemm_kernel<false, 1>), dim3(256), dim3(256), 0, stream,
                       (const void*)h1b, W2b, Gbuf);
    hipLaunchKernelGGL((agg_kernel<true, 1>), dim3(NN / 2), dim3(256), 0, stream,
                       Gbuf, b2, (void*)out, cnt, bucket);
}

// Round 12
// 103.719 us; speedup vs baseline: 1.1492x; 1.1492x over previous
//
#include <hip/hip_runtime.h>
#include <hip/hip_bf16.h>
#include <cstdint>
#include <cstddef>

#define NN 10000
#define NE 160000
#define DD 300
#define KP 320      // K padded to 10 MFMA steps of 32
#define NPAD 320    // W rows padded to 20 tiles of 16
#define MTILES 625  // NN/16
#define CAP 64      // bucket capacity per node (max degree ~35 for this graph)

using bf16x8 = __attribute__((ext_vector_type(8))) __bf16;
using f32x4  = __attribute__((ext_vector_type(4))) float;

// ---------------- K1: zero cnt + convert W1,W2 -> bf16 [NPAD][KP] ----------------

__global__ __launch_bounds__(256) void zero_convw_kernel(const float* __restrict__ W1,
                                                         const float* __restrict__ W2,
                                                         __bf16* __restrict__ W1b,
                                                         __bf16* __restrict__ W2b,
                                                         int* __restrict__ cnt) {
    const int t = blockIdx.x * 256 + threadIdx.x;   // 0..12799
    if (t < NN) cnt[t] = 0;
    const int n = t / (KP / 8);          // 0..319
    const int k0 = (t % (KP / 8)) * 8;   // 0..312
    bf16x8 v1, v2;
#pragma unroll
    for (int i = 0; i < 8; ++i) {
        const int k = k0 + i;
        const bool in = (n < DD) && (k < DD);
        v1[i] = (__bf16)(in ? W1[n * DD + k] : 0.f);
        v2[i] = (__bf16)(in ? W2[n * DD + k] : 0.f);
    }
    *(bf16x8*)(W1b + (size_t)n * KP + k0) = v1;
    *(bf16x8*)(W2b + (size_t)n * KP + k0) = v2;
}

// ---------------- K2: bucket fill ----------------

__global__ void bucket_kernel(const int* __restrict__ src, const int* __restrict__ dst,
                              int* __restrict__ cnt, int* __restrict__ bucket) {
    int e = blockIdx.x * 256 + threadIdx.x;
    if (e < NE) {
        int d = dst[e];
        int pos = atomicAdd(&cnt[d], 1);
        if (pos < CAP) bucket[d * CAP + pos] = src[e];
    }
}

// ---------------- GEMM: G[m][n] = fp8(sum_k A[m][k]*W[n][k])  (fp8 e4m3fn out) ----------------
// W-stationary: wave w holds B frags for N-tiles w*5..w*5+4 in registers.
// F32IN: A is f32 [NN][DD] (features); else bf16 [NN][KP].

template <bool F32IN>
__global__ __launch_bounds__(256, 1) void gemm_kernel(const void* __restrict__ Ap,
                                                      const __bf16* __restrict__ Wb,
                                                      unsigned char* __restrict__ G) {
    const int w = threadIdx.x >> 6;
    const int lane = threadIdx.x & 63;
    const int r = lane & 15;    // A row-in-tile / B col / D col
    const int q = lane >> 4;    // k-block select / D row-block

    bf16x8 b[5][10];
    const __bf16* Bb = Wb + (size_t)r * KP + q * 8;
#pragma unroll
    for (int t = 0; t < 5; ++t) {
        const __bf16* Bt = Bb + (size_t)(w * 5 + t) * 16 * KP;
#pragma unroll
        for (int ks = 0; ks < 10; ++ks)
            b[t][ks] = *(const bf16x8*)(Bt + ks * 32);
    }

    for (int mt = blockIdx.x; mt < MTILES; mt += gridDim.x) {
        f32x4 acc[5] = {};
        if constexpr (F32IN) {
            const float* Ab = (const float*)Ap + (size_t)(mt * 16 + r) * DD + q * 8;
#pragma unroll
            for (int ks = 0; ks < 9; ++ks) {   // k0+7 <= 287 < 300: full vectors
                f32x4 lo = *(const f32x4*)(Ab + ks * 32);
                f32x4 hi = *(const f32x4*)(Ab + ks * 32 + 4);
                bf16x8 af;
#pragma unroll
                for (int j = 0; j < 4; ++j) { af[j] = (__bf16)lo[j]; af[4 + j] = (__bf16)hi[j]; }
#pragma unroll
                for (int t = 0; t < 5; ++t)
                    acc[t] = __builtin_amdgcn_mfma_f32_16x16x32_bf16(af, b[t][ks], acc[t], 0, 0, 0);
            }
            {   // ks = 9: k = 288 + q*8 + j, guard k < 300
                bf16x8 af;
#pragma unroll
                for (int j = 0; j < 8; ++j) {
                    int k = 288 + q * 8 + j;
                    af[j] = (__bf16)((k < DD) ? Ab[288 + j] : 0.f);
                }
#pragma unroll
                for (int t = 0; t < 5; ++t)
                    acc[t] = __builtin_amdgcn_mfma_f32_16x16x32_bf16(af, b[t][9], acc[t], 0, 0, 0);
            }
        } else {
            const __bf16* Ab = (const __bf16*)Ap + (size_t)(mt * 16 + r) * KP + q * 8;
#pragma unroll
            for (int ks = 0; ks < 10; ++ks) {
                bf16x8 af = *(const bf16x8*)(Ab + ks * 32);
#pragma unroll
                for (int t = 0; t < 5; ++t)
                    acc[t] = __builtin_amdgcn_mfma_f32_16x16x32_bf16(af, b[t][ks], acc[t], 0, 0, 0);
            }
        }
#pragma unroll
        for (int t = 0; t < 5; ++t) {
            const int n = (w * 5 + t) * 16 + r;
#pragma unroll
            for (int j = 0; j < 4; ++j) {
                const int m = mt * 16 + q * 4 + j;
                // f32 -> fp8 e4m3fn (RNE + saturate), native pack, take byte 0
                unsigned int p8 = (unsigned int)__builtin_amdgcn_cvt_pk_fp8_f32(
                    acc[t][j], acc[t][j], 0, false);
                G[(size_t)m * KP + n] = (unsigned char)(p8 & 0xffu);
            }
        }
    }
}

// ---------------- aggregation over fp8 G + bias + relu; 2 nodes x 2 waves (R7 structure) ----------------
// out[n] = relu(G[n] + sum_{e:dst=n} G[src[e]] + b)
// fp8 row = 320 B: lane l in [0,40) loads uint2 (8 fp8) at l*8. Manual e4m3fn decode:
// as_float(((b&0x80)<<24) | ((b&0x7f)<<20)) * 2^120  (fp8 subnormals flush ~0, err < 2^-6).
// LAST: f32 [NN][DD] out; else bf16 [NN][KP] out with zero pads.

template <bool LAST>
__global__ __launch_bounds__(256) void agg_kernel(const unsigned char* __restrict__ G,
                                                  const float* __restrict__ bias,
                                                  void* __restrict__ outp,
                                                  const int* __restrict__ cnt,
                                                  const int* __restrict__ bucket) {
    __shared__ float part[2][KP];
    const int w = threadIdx.x >> 6;        // 0..3
    const int lane = threadIdx.x & 63;
    const int nsub = w >> 1;               // node slot in block
    const int half = w & 1;                // 0: self + first half; 1: second half
    const int node = blockIdx.x * 2 + nsub;   // grid 5000 x 2 = 10000 exactly
    const bool act = lane < (KP / 8);      // 40 lanes x 8 fp8 = 320 B row
    const uint2* hv = (const uint2*)G;     // row stride KP/8 = 40 uint2

    const int c = min(cnt[node], CAP);
    const int h0 = c >> 1;
    const int myBase = node * CAP + (half ? h0 : 0);
    const int myCnt = half ? (c - h0) : h0;

    float acc[8] = {};
    auto dec = [](unsigned int b) -> float {
        unsigned int f = ((b & 0x80u) << 24) | ((b & 0x7fu) << 20);
        return __uint_as_float(f) * 0x1p+120f;
    };
    auto addv = [&](uint2 v) {
#pragma unroll
        for (int i = 0; i < 4; ++i) {
            acc[i]     += dec((v.x >> (8 * i)) & 0xffu);
            acc[4 + i] += dec((v.y >> (8 * i)) & 0xffu);
        }
    };

    if (!half && act) addv(hv[(size_t)node * (KP / 8) + lane]);   // self-loop

    int idx = 0;
    if (lane < myCnt) idx = bucket[myBase + lane];
    int j = 0;
    for (; j + 4 <= myCnt; j += 4) {       // 4 gathers in flight
        int n0 = __shfl(idx, j),     n1 = __shfl(idx, j + 1);
        int n2 = __shfl(idx, j + 2), n3 = __shfl(idx, j + 3);
        if (act) {
            uint2 v0 = hv[(size_t)n0 * (KP / 8) + lane];
            uint2 v1 = hv[(size_t)n1 * (KP / 8) + lane];
            uint2 v2 = hv[(size_t)n2 * (KP / 8) + lane];
            uint2 v3 = hv[(size_t)n3 * (KP / 8) + lane];
            addv(v0); addv(v1); addv(v2); addv(v3);
        }
    }
    for (; j < myCnt; ++j) {
        int nb = __shfl(idx, j);
        if (act) addv(hv[(size_t)nb * (KP / 8) + lane]);
    }

    // combine wave pair through LDS
    if (half && act) {
        *(f32x4*)&part[nsub][lane * 8]     = (f32x4){acc[0], acc[1], acc[2], acc[3]};
        *(f32x4*)&part[nsub][lane * 8 + 4] = (f32x4){acc[4], acc[5], acc[6], acc[7]};
    }
    __syncthreads();
    if (half || !act) return;

    f32x4 p0 = *(const f32x4*)&part[nsub][lane * 8];
    f32x4 p1 = *(const f32x4*)&part[nsub][lane * 8 + 4];
#pragma unroll
    for (int i = 0; i < 4; ++i) { acc[i] += p0[i]; acc[4 + i] += p1[i]; }

    const int c0 = lane * 8;
    if (LAST) {
        float* out = (float*)outp + (size_t)node * DD + c0;
#pragma unroll
        for (int i = 0; i < 8; ++i) {
            int n = c0 + i;
            if (n < DD) {
                float v = acc[i] + bias[n];
                out[i] = v > 0.f ? v : 0.f;
            }
        }
    } else {
        bf16x8 o;
#pragma unroll
        for (int i = 0; i < 8; ++i) {
            int n = c0 + i;
            float v = (n < DD) ? acc[i] + bias[n] : 0.f;
            v = v > 0.f ? v : 0.f;
            o[i] = (__bf16)v;
        }
        *(bf16x8*)((__bf16*)outp + (size_t)node * KP + c0) = o;
    }
}

// ---------------- launch ----------------

extern "C" void kernel_launch(void* const* d_in, const int* in_sizes, int n_in,
                              void* d_out, int out_size, void* d_ws, size_t ws_size,
                              hipStream_t stream) {
    const float* features = (const float*)d_in[0];
    const int*   src      = (const int*)d_in[1];
    const int*   dst      = (const int*)d_in[2];
    const float* W1       = (const float*)d_in[3];
    const float* b1       = (const float*)d_in[4];
    const float* W2       = (const float*)d_in[5];
    const float* b2       = (const float*)d_in[6];
    float* out = (float*)d_out;

    char* ws = (char*)d_ws;
    size_t off = 0;
    auto alloc = [&](size_t bytes) -> void* {
        void* p = ws + off;
        off += (bytes + 255) & ~(size_t)255;
        return p;
    };
    int*    cnt    = (int*)alloc(NN * sizeof(int));
    int*    bucket = (int*)alloc((size_t)NN * CAP * sizeof(int));
    __bf16* W1b    = (__bf16*)alloc((size_t)NPAD * KP * sizeof(__bf16));
    __bf16* W2b    = (__bf16*)alloc((size_t)NPAD * KP * sizeof(__bf16));
    unsigned char* Gbuf = (unsigned char*)alloc((size_t)NN * KP);   // fp8 G, 3.2 MB (< 4 MB/XCD L2)
    __bf16* h1b    = (__bf16*)alloc((size_t)NN * KP * sizeof(__bf16));
    (void)ws_size; (void)in_sizes; (void)n_in; (void)out_size;

    // K1: zero cnt + convert W
    hipLaunchKernelGGL(zero_convw_kernel, dim3(50), dim3(256), 0, stream, W1, W2, W1b, W2b, cnt);
    // K2: bucket fill
    hipLaunchKernelGGL(bucket_kernel, dim3((NE + 255) / 256), dim3(256), 0, stream, src, dst, cnt, bucket);

    // layer 1: G1 = fp8(features . W1^T) ; h1 = relu(agg(G1) + b1)
    hipLaunchKernelGGL((gemm_kernel<true>), dim3(256), dim3(256), 0, stream,
                       (const void*)features, W1b, Gbuf);
    hipLaunchKernelGGL((agg_kernel<false>), dim3(NN / 2), dim3(256), 0, stream,
                       Gbuf, b1, (void*)h1b, cnt, bucket);
    // layer 2: G2 = fp8(h1 . W2^T) ; out = relu(agg(G2) + b2)
    hipLaunchKernelGGL((gemm_kernel<false>), dim3(256), dim3(256), 0, stream,
                       (const void*)h1b, W2b, Gbuf);
    hipLaunchKernelGGL((agg_kernel<true>), dim3(NN / 2), dim3(256), 0, stream,
                       Gbuf, b2, (void*)out, cnt, bucket);
}